// Round 1
// baseline (298.237 us; speedup 1.0000x reference)
//
#include <hip/hip_runtime.h>

#define B_ 4
#define S_ 4096
#define D_ 256
#define BM 64
#define BN 64
#define NSPLIT 2
#define SKEYS (S_/NSPLIT)   // 2048 keys per split
#define ITERS (SKEYS/BN)    // 32

typedef short v8s __attribute__((ext_vector_type(8)));
typedef float v16f __attribute__((ext_vector_type(16)));

__device__ __forceinline__ unsigned short f2bf(float x){
    unsigned int u = __float_as_uint(x);
    u += 0x7fffu + ((u >> 16) & 1u);          // RNE
    return (unsigned short)(u >> 16);
}
__device__ __forceinline__ unsigned int pk2(float a, float b){
    return (unsigned int)f2bf(a) | ((unsigned int)f2bf(b) << 16);
}

// ---------- convert Q (scaled 1/16) and K to bf16 ----------
__global__ void cvt_qk(const float* __restrict__ q, const float* __restrict__ k,
                       uint4* __restrict__ qb, uint4* __restrict__ kb){
    int gid = blockIdx.x * 256 + threadIdx.x;     // 2048 blocks: 8 elems each tensor
    const float4* qp = (const float4*)q + (size_t)gid * 2;
    float4 a0 = qp[0], a1 = qp[1];
    const float sc = 0.0625f;                     // 1/sqrt(256), exact in bf16 scaling
    uint4 o;
    o.x = pk2(a0.x*sc, a0.y*sc); o.y = pk2(a0.z*sc, a0.w*sc);
    o.z = pk2(a1.x*sc, a1.y*sc); o.w = pk2(a1.z*sc, a1.w*sc);
    qb[gid] = o;
    const float4* kp = (const float4*)k + (size_t)gid * 2;
    float4 b0 = kp[0], b1 = kp[1];
    uint4 o2;
    o2.x = pk2(b0.x, b0.y); o2.y = pk2(b0.z, b0.w);
    o2.z = pk2(b1.x, b1.y); o2.w = pk2(b1.z, b1.w);
    kb[gid] = o2;
}

// ---------- V (b,s,d) fp32 -> Vt (b,d,s) bf16 ----------
__global__ void cvt_v_t(const float* __restrict__ v, unsigned short* __restrict__ vt){
    __shared__ __align__(16) float tile[64][68];  // 64x64 fp32 tile, padded
    int bid = blockIdx.x;                          // 4 * 64 * 4 = 1024 blocks
    int dt = bid & 3;
    int st = (bid >> 2) & 63;
    int b  = bid >> 8;
    int t = threadIdx.x;
    int s0 = st * 64, d0 = dt * 64;
    #pragma unroll
    for (int p = 0; p < 4; ++p){
        int idx = t + 256*p;
        int r = idx >> 4, c4 = idx & 15;
        float4 f = *(const float4*)(v + (size_t)(b*S_ + s0 + r)*D_ + d0 + c4*4);
        *(float4*)&tile[r][c4*4] = f;
    }
    __syncthreads();
    #pragma unroll
    for (int p = 0; p < 2; ++p){
        int idx = t + 256*p;
        int rr = idx >> 3, c8 = idx & 7;          // rr: d-row in tile, c8: s-chunk of 8
        float f0 = tile[c8*8+0][rr], f1 = tile[c8*8+1][rr];
        float f2 = tile[c8*8+2][rr], f3 = tile[c8*8+3][rr];
        float f4 = tile[c8*8+4][rr], f5 = tile[c8*8+5][rr];
        float f6 = tile[c8*8+6][rr], f7 = tile[c8*8+7][rr];
        uint4 o;
        o.x = pk2(f0,f1); o.y = pk2(f2,f3); o.z = pk2(f4,f5); o.w = pk2(f6,f7);
        *(uint4*)(vt + (size_t)(b*D_ + d0 + rr)*S_ + s0 + c8*8) = o;
    }
}

// ---------- main flash-attention kernel ----------
__global__ __launch_bounds__(256, 2) void fa_main(
    const unsigned short* __restrict__ qb, const unsigned short* __restrict__ kb,
    const unsigned short* __restrict__ vtg,
    float* __restrict__ opart, float* __restrict__ mpart, float* __restrict__ lpart)
{
    // LDS: uniform bank spread, all vector ops 16B-aligned
    __shared__ __align__(16) unsigned short Ks[64][264];   // 64 keys x 256 d  (528B rows)
    __shared__ __align__(16) unsigned short Vs[256][72];   // 256 d  x 64 keys (144B rows)
    __shared__ __align__(16) unsigned short Ps[2][32][72]; // per q-tile: 32 q x 64 keys
    __shared__ float smax[2][2][32];
    __shared__ float ssum[2][2][32];

    int bid = blockIdx.x;
    int b     = bid & 3;           // batch -> XCD slot (bid%8 = (split<<2)|b): K/V half fits 4MB L2
    int split = (bid >> 2) & 1;
    int qt    = bid >> 3;
    int q0 = qt * BM;
    int tid = threadIdx.x;
    int w = tid >> 6, lane = tid & 63, hi = lane >> 5, ln = lane & 31;
    int i = w & 1;                 // q-tile (32 queries)
    int j = w >> 1;                // key-half for S phase / d-half for PV phase

    const unsigned short* qbase = qb  + ((size_t)(b*S_) + q0) * D_;
    const unsigned short* kbase = kb  + ((size_t)(b*S_) + split*SKEYS) * D_;
    const unsigned short* vbase = vtg + ((size_t)(b*D_)) * S_ + split*SKEYS;

    // stage Q tile into Ks, pull B-operand fragments into registers
    #pragma unroll
    for (int p = 0; p < 8; ++p){
        int idx = tid + 256*p;
        int r = idx >> 5, c = idx & 31;
        *(uint4*)&Ks[r][c*8] = *(const uint4*)(qbase + (size_t)r*D_ + c*8);
    }
    __syncthreads();
    v8s qf[16];
    #pragma unroll
    for (int f = 0; f < 16; ++f)
        qf[f] = *(const v8s*)&Ks[i*32 + ln][(2*f + hi)*8];   // B[k=d][n=q]

    v16f oacc[4];
    #pragma unroll
    for (int t = 0; t < 4; ++t)
        #pragma unroll
        for (int r = 0; r < 16; ++r) oacc[t][r] = 0.0f;
    float m_run = -1e30f, l_run = 0.0f;

    for (int it = 0; it < ITERS; ++it){
        __syncthreads();   // previous iter done reading Ks/Vs (and Q-frag reads, iter 0)
        const unsigned short* kk = kbase + (size_t)(it*BN)*D_;
        #pragma unroll
        for (int p = 0; p < 8; ++p){
            int idx = tid + 256*p;
            int r = idx >> 5, c = idx & 31;
            *(uint4*)&Ks[r][c*8] = *(const uint4*)(kk + (size_t)r*D_ + c*8);
        }
        const unsigned short* vv = vbase + it*BN;
        #pragma unroll
        for (int p = 0; p < 8; ++p){
            int idx = tid + 256*p;
            int d = idx >> 3, c = idx & 7;
            *(uint4*)&Vs[d][c*8] = *(const uint4*)(vv + (size_t)d*S_ + c*8);
        }
        __syncthreads();

        // S^T tile: C[m=key][n=q], col(lane&31) = query -> softmax state uniform per lane
        v16f sc2;
        #pragma unroll
        for (int r = 0; r < 16; ++r) sc2[r] = 0.0f;
        #pragma unroll
        for (int f = 0; f < 16; ++f){
            v8s a = *(const v8s*)&Ks[j*32 + ln][(2*f + hi)*8];   // A[m=key][k=d]
            sc2 = __builtin_amdgcn_mfma_f32_32x32x16_bf16(a, qf[f], sc2, 0, 0, 0);
        }

        // online softmax: cross-wave max
        float mx = -1e30f;
        #pragma unroll
        for (int r = 0; r < 16; ++r) mx = fmaxf(mx, sc2[r]);
        mx = fmaxf(mx, __shfl_xor(mx, 32));
        if (lane < 32) smax[j][i][ln] = mx;
        __syncthreads();
        float m_new = fmaxf(m_run, fmaxf(smax[0][i][ln], smax[1][i][ln]));
        float alpha = __expf(m_run - m_new);
        m_run = m_new;

        float pv[16]; float ls = 0.0f;
        #pragma unroll
        for (int r = 0; r < 16; ++r){ pv[r] = __expf(sc2[r] - m_new); ls += pv[r]; }
        ls += __shfl_xor(ls, 32);
        if (lane < 32) ssum[j][i][ln] = ls;

        // P -> LDS as P[q][key] bf16 (rows = query, so PV B-frag is contiguous b128)
        #pragma unroll
        for (int g = 0; g < 4; ++g){
            uint2 w2;
            w2.x = pk2(pv[4*g+0], pv[4*g+1]);
            w2.y = pk2(pv[4*g+2], pv[4*g+3]);
            *(uint2*)&Ps[i][ln][j*32 + 8*g + 4*hi] = w2;   // keys (reg&3)+8*(reg>>2)+4*hi
        }
        // rescale accumulator (alpha uniform per lane: col = query)
        #pragma unroll
        for (int t = 0; t < 4; ++t)
            #pragma unroll
            for (int r = 0; r < 16; ++r) oacc[t][r] *= alpha;
        l_run *= alpha;
        __syncthreads();
        l_run += ssum[0][i][ln] + ssum[1][i][ln];

        // O^T += V^T * P : C[m=d][n=q]
        #pragma unroll
        for (int ks = 0; ks < 4; ++ks){
            v8s pb = *(const v8s*)&Ps[i][ln][ks*16 + hi*8];          // B[k=key][n=q]
            #pragma unroll
            for (int t = 0; t < 4; ++t){
                v8s av = *(const v8s*)&Vs[j*128 + t*32 + ln][(2*ks + hi)*8]; // A[m=d][k=key]
                oacc[t] = __builtin_amdgcn_mfma_f32_32x32x16_bf16(av, pb, oacc[t], 0, 0, 0);
            }
        }
    }

    // epilogue: unnormalized O + (m,l) stats for the split merge
    size_t orow = (size_t)(split*B_ + b) * S_ + q0 + i*32 + ln;
    if (j == 0 && lane < 32){
        mpart[orow] = m_run;
        lpart[orow] = l_run;
    }
    float* obase = opart + orow * D_ + j*128;
    #pragma unroll
    for (int t = 0; t < 4; ++t){
        #pragma unroll
        for (int g = 0; g < 4; ++g){
            float4 o4 = make_float4(oacc[t][4*g+0], oacc[t][4*g+1],
                                    oacc[t][4*g+2], oacc[t][4*g+3]);
            *(float4*)(obase + t*32 + 8*g + 4*hi) = o4;   // d = t*32 + 8g + e + 4*hi
        }
    }
}

// ---------- merge the two K-splits ----------
__global__ void merge_k(const float* __restrict__ opart, const float* __restrict__ mpart,
                        const float* __restrict__ lpart, float* __restrict__ out){
    int gid = blockIdx.x * 256 + threadIdx.x;     // 4096 blocks, 4 floats/thread
    size_t idx4 = (size_t)gid * 4;
    int row = (int)(idx4 >> 8);                   // b*S + q
    float m0 = mpart[row], m1 = mpart[row + B_*S_];
    float l0 = lpart[row], l1 = lpart[row + B_*S_];
    float mm = fmaxf(m0, m1);
    float a0 = __expf(m0 - mm), a1 = __expf(m1 - mm);
    float inv = 1.0f / (a0*l0 + a1*l1);
    float4 o0 = *(const float4*)(opart + idx4);
    float4 o1 = *(const float4*)(opart + idx4 + (size_t)B_*S_*D_);
    float4 r;
    r.x = (a0*o0.x + a1*o1.x) * inv;
    r.y = (a0*o0.y + a1*o1.y) * inv;
    r.z = (a0*o0.z + a1*o1.z) * inv;
    r.w = (a0*o0.w + a1*o1.w) * inv;
    *(float4*)(out + idx4) = r;
}

extern "C" void kernel_launch(void* const* d_in, const int* in_sizes, int n_in,
                              void* d_out, int out_size, void* d_ws, size_t ws_size,
                              hipStream_t stream){
    const float* q = (const float*)d_in[0];
    const float* k = (const float*)d_in[1];
    const float* v = (const float*)d_in[2];
    char* ws = (char*)d_ws;
    // ws layout (bytes): Qb 8MB | Kb 8MB | Vt 8MB | Opart 32MB | Mpart 128KB | Lpart 128KB
    uint4* qb = (uint4*)(ws);
    uint4* kb = (uint4*)(ws + 8388608);
    unsigned short* vt = (unsigned short*)(ws + 16777216);
    float* opart = (float*)(ws + 25165824);
    float* mpart = (float*)(ws + 58720256);
    float* lpart = (float*)(ws + 58851328);

    cvt_qk<<<dim3(2048), dim3(256), 0, stream>>>(q, k, qb, kb);
    cvt_v_t<<<dim3(1024), dim3(256), 0, stream>>>(v, vt);
    fa_main<<<dim3(512), dim3(256), 0, stream>>>((const unsigned short*)qb,
                                                 (const unsigned short*)kb, vt,
                                                 opart, mpart, lpart);
    merge_k<<<dim3(4096), dim3(256), 0, stream>>>(opart, mpart, lpart, (float*)d_out);
}

// Round 2
// 279.994 us; speedup vs baseline: 1.0652x; 1.0652x over previous
//
#include <hip/hip_runtime.h>

#define B_ 4
#define S_ 4096
#define D_ 256
#define BM 128
#define BN 64
#define NSPLIT 4
#define SKEYS (S_/NSPLIT)   // 1024 keys per split
#define ITERS (SKEYS/BN)    // 16

typedef short v8s __attribute__((ext_vector_type(8)));
typedef float v16f __attribute__((ext_vector_type(16)));

__device__ __forceinline__ unsigned short f2bf(float x){
    unsigned int u = __float_as_uint(x);
    u += 0x7fffu + ((u >> 16) & 1u);          // RNE
    return (unsigned short)(u >> 16);
}
__device__ __forceinline__ unsigned int pk2(float a, float b){
    return (unsigned int)f2bf(a) | ((unsigned int)f2bf(b) << 16);
}
__device__ __forceinline__ float bf2f(unsigned int lo16){
    return __uint_as_float(lo16 << 16);
}
// async global->LDS, 16B per lane; LDS dest = wave-uniform base + lane*16
__device__ __forceinline__ void gload_lds(const unsigned short* g, unsigned short* l){
    __builtin_amdgcn_global_load_lds(
        (const __attribute__((address_space(1))) unsigned int*)g,
        (__attribute__((address_space(3))) unsigned int*)l, 16, 0, 0);
}

// ---------- convert Q (scaled 1/16) and K to bf16 ----------
__global__ void cvt_qk(const float* __restrict__ q, const float* __restrict__ k,
                       uint4* __restrict__ qb, uint4* __restrict__ kb){
    int gid = blockIdx.x * 256 + threadIdx.x;
    const float4* qp = (const float4*)q + (size_t)gid * 2;
    float4 a0 = qp[0], a1 = qp[1];
    const float sc = 0.0625f;
    uint4 o;
    o.x = pk2(a0.x*sc, a0.y*sc); o.y = pk2(a0.z*sc, a0.w*sc);
    o.z = pk2(a1.x*sc, a1.y*sc); o.w = pk2(a1.z*sc, a1.w*sc);
    qb[gid] = o;
    const float4* kp = (const float4*)k + (size_t)gid * 2;
    float4 b0 = kp[0], b1 = kp[1];
    uint4 o2;
    o2.x = pk2(b0.x, b0.y); o2.y = pk2(b0.z, b0.w);
    o2.z = pk2(b1.x, b1.y); o2.w = pk2(b1.z, b1.w);
    kb[gid] = o2;
}

// ---------- V (b,s,d) fp32 -> Vt (b,d,s) bf16, LDS-free ----------
// thread: one s, 16 d. reads full 64B line per lane; writes 64-lane-contiguous 2B.
__global__ void cvt_v_t(const float* __restrict__ v, unsigned short* __restrict__ vt){
    int bid = blockIdx.x;                  // b(2) | dblk(2) | sblk(6) -> 1024 blocks
    int b    = bid >> 8;
    int dblk = (bid >> 6) & 3;
    int sblk = bid & 63;
    int t = threadIdx.x;
    int s  = sblk*64 + (t & 63);
    int d0 = (dblk*4 + (t >> 6)) * 16;
    const float* src = v + ((size_t)(b*S_ + s))*D_ + d0;
    float4 f[4];
    #pragma unroll
    for (int i = 0; i < 4; ++i) f[i] = ((const float4*)src)[i];
    unsigned short* dst = vt + (size_t)(b*D_ + d0)*S_ + s;
    #pragma unroll
    for (int i = 0; i < 4; ++i){
        dst[(size_t)(4*i+0)*S_] = f2bf(f[i].x);
        dst[(size_t)(4*i+1)*S_] = f2bf(f[i].y);
        dst[(size_t)(4*i+2)*S_] = f2bf(f[i].z);
        dst[(size_t)(4*i+3)*S_] = f2bf(f[i].w);
    }
}

// ---------- main flash-attention kernel ----------
// 256 thr = 4 waves; each wave: 32 queries x all 64 keys/iter x full d=256.
// LDS rows unpadded (512B / 128B); bank conflicts broken by chunk ^= (row&7).
__global__ __launch_bounds__(256, 2) void fa_main(
    const unsigned short* __restrict__ qb, const unsigned short* __restrict__ kb,
    const unsigned short* __restrict__ vtg,
    unsigned short* __restrict__ opart, float* __restrict__ lsep)
{
    __shared__ __align__(16) unsigned short Ks[64*256];   // 32 KB
    __shared__ __align__(16) unsigned short Vs[256*64];   // 32 KB

    int bid = blockIdx.x;
    int grp = bid & 15;                 // (b*4+split): fixed XCD slot per K/V group
    int qt  = bid >> 4;
    int b = grp >> 2, split = grp & 3;
    int q0 = qt * BM;
    int tid = threadIdx.x;
    int w = tid >> 6, lane = tid & 63, hi = lane >> 5, ln = lane & 31;
    int m7 = ln & 7;

    const unsigned short* qg = qb  + ((size_t)(b*S_) + q0) * D_;
    const unsigned short* kg = kb  + ((size_t)(b*S_) + split*SKEYS) * D_;
    const unsigned short* vg = vtg + (size_t)(b*D_)*S_ + split*SKEYS;

    // ---- stage Q through Ks in two rounds; pull B-frags (lane ln = query) ----
    v8s qf[16];
    #pragma unroll
    for (int r = 0; r < 2; ++r){
        __syncthreads();
        #pragma unroll
        for (int p = 0; p < 8; ++p){
            int row  = 16*w + 2*p;                 // local row in Ks
            int grow = 64*r + row + (lane >> 5);   // q row within tile
            int slot = lane & 31;
            gload_lds(qg + (size_t)grow*D_ + ((slot ^ (grow & 7)) * 8), &Ks[row*256]);
        }
        __syncthreads();
        if ((w >> 1) == r){
            int rl = 32*(w & 1) + ln;
            #pragma unroll
            for (int f = 0; f < 16; ++f)
                qf[f] = *(const v8s*)&Ks[rl*256 + (((2*f + hi) ^ m7) * 8)];
        }
    }

    v16f oacc[8];
    #pragma unroll
    for (int t = 0; t < 8; ++t)
        #pragma unroll
        for (int r = 0; r < 16; ++r) oacc[t][r] = 0.0f;
    float m_run = -1e30f, l_run = 0.0f;

    for (int it = 0; it < ITERS; ++it){
        __syncthreads();                           // all waves done reading prev tile
        const unsigned short* kk = kg + (size_t)(it*BN)*D_;
        #pragma unroll
        for (int p = 0; p < 8; ++p){               // K: wave w stages keys 16w..16w+15
            int row  = 16*w + 2*p;
            int krow = row + (lane >> 5);
            int slot = lane & 31;
            gload_lds(kk + (size_t)krow*D_ + ((slot ^ (krow & 7)) * 8), &Ks[row*256]);
        }
        const unsigned short* vv = vg + it*BN;
        #pragma unroll
        for (int p = 0; p < 8; ++p){               // V: wave w stages d 64w..64w+63
            int d0 = 64*w + 8*p;
            int dd = d0 + (lane >> 3);
            int slot = lane & 7;
            gload_lds(vv + (size_t)dd*S_ + ((slot ^ (dd & 7)) * 8), &Vs[d0*64]);
        }
        __syncthreads();

        // ---- S^T = K·Q^T : two 32-key tiles, col(lane&31)=query ----
        v16f s0, s1;
        #pragma unroll
        for (int r = 0; r < 16; ++r){ s0[r] = 0.0f; s1[r] = 0.0f; }
        #pragma unroll
        for (int f = 0; f < 16; ++f){
            int sl = ((2*f + hi) ^ m7) * 8;
            v8s a0 = *(const v8s*)&Ks[ln*256 + sl];
            v8s a1 = *(const v8s*)&Ks[(32 + ln)*256 + sl];
            s0 = __builtin_amdgcn_mfma_f32_32x32x16_bf16(a0, qf[f], s0, 0, 0, 0);
            s1 = __builtin_amdgcn_mfma_f32_32x32x16_bf16(a1, qf[f], s1, 0, 0, 0);
        }

        // ---- wave-local online softmax (no barriers) ----
        float mx = s0[0];
        #pragma unroll
        for (int r = 1; r < 16; ++r) mx = fmaxf(mx, s0[r]);
        #pragma unroll
        for (int r = 0; r < 16; ++r) mx = fmaxf(mx, s1[r]);
        mx = fmaxf(mx, __shfl_xor(mx, 32));
        float m_new = fmaxf(m_run, mx);
        float alpha = __expf(m_run - m_new);
        m_run = m_new;

        float ls = 0.0f;
        uint2 pA[4], pB[4];
        #pragma unroll
        for (int c = 0; c < 4; ++c){
            float e0 = __expf(s0[4*c+0] - m_new), e1 = __expf(s0[4*c+1] - m_new);
            float e2 = __expf(s0[4*c+2] - m_new), e3 = __expf(s0[4*c+3] - m_new);
            ls += (e0 + e1) + (e2 + e3);
            pA[c].x = pk2(e0, e1); pA[c].y = pk2(e2, e3);
            float g0 = __expf(s1[4*c+0] - m_new), g1 = __expf(s1[4*c+1] - m_new);
            float g2 = __expf(s1[4*c+2] - m_new), g3 = __expf(s1[4*c+3] - m_new);
            ls += (g0 + g1) + (g2 + g3);
            pB[c].x = pk2(g0, g1); pB[c].y = pk2(g2, g3);
        }
        ls += __shfl_xor(ls, 32);
        l_run = l_run * alpha + ls;

        // ---- P: C-layout -> B-operand via lane^32 quad exchange ----
        v8s pf[4];
        #pragma unroll
        for (int ks = 0; ks < 4; ++ks){
            int k1 = ks & 1;
            uint2 q0v = (ks < 2) ? pA[2*k1]     : pB[2*k1];
            uint2 q1v = (ks < 2) ? pA[2*k1 + 1] : pB[2*k1 + 1];
            uint2 own = hi ? q1v : q0v;
            uint2 snd = hi ? q0v : q1v;
            uint2 rcv;
            rcv.x = (unsigned int)__shfl_xor((int)snd.x, 32);
            rcv.y = (unsigned int)__shfl_xor((int)snd.y, 32);
            uint2 lo = hi ? rcv : own;
            uint2 hb = hi ? own : rcv;
            union { unsigned int u[4]; v8s v; } cc;
            cc.u[0] = lo.x; cc.u[1] = lo.y; cc.u[2] = hb.x; cc.u[3] = hb.y;
            pf[ks] = cc.v;
        }

        // rescale O (alpha uniform per lane: col = query)
        #pragma unroll
        for (int t = 0; t < 8; ++t)
            #pragma unroll
            for (int r = 0; r < 16; ++r) oacc[t][r] *= alpha;

        // ---- O^T += V^T · P ----
        #pragma unroll
        for (int ks = 0; ks < 4; ++ks){
            int slv = ((2*ks + hi) ^ m7) * 8;
            #pragma unroll
            for (int t = 0; t < 8; ++t){
                v8s av = *(const v8s*)&Vs[(t*32 + ln)*64 + slv];
                oacc[t] = __builtin_amdgcn_mfma_f32_32x32x16_bf16(av, pf[ks], oacc[t], 0, 0, 0);
            }
        }
    }

    // ---- epilogue: normalized bf16 partial + LSE ----
    size_t orow = (size_t)(split*B_ + b)*S_ + q0 + w*32 + ln;
    if (hi == 0) lsep[orow] = m_run + __logf(l_run);
    float inv = 1.0f / l_run;
    unsigned short* ob = opart + orow * D_;
    #pragma unroll
    for (int t = 0; t < 8; ++t){
        #pragma unroll
        for (int g = 0; g < 4; ++g){
            uint2 u;
            u.x = pk2(oacc[t][4*g+0]*inv, oacc[t][4*g+1]*inv);
            u.y = pk2(oacc[t][4*g+2]*inv, oacc[t][4*g+3]*inv);
            *(uint2*)(ob + t*32 + 8*g + 4*hi) = u;
        }
    }
}

// ---------- merge the 4 K-splits (LSE-weighted) ----------
__global__ void merge_k(const unsigned short* __restrict__ opart,
                        const float* __restrict__ lsep, float* __restrict__ out){
    int gid = blockIdx.x * 256 + threadIdx.x;   // 2048 blocks
    int row = gid >> 5;                         // b*S + q
    int dc  = (gid & 31) * 8;
    float L[4];
    #pragma unroll
    for (int s = 0; s < 4; ++s) L[s] = lsep[s*(B_*S_) + row];
    float mm = fmaxf(fmaxf(L[0], L[1]), fmaxf(L[2], L[3]));
    float ws[4], tot = 0.0f;
    #pragma unroll
    for (int s = 0; s < 4; ++s){ ws[s] = __expf(L[s] - mm); tot += ws[s]; }
    float inv = 1.0f / tot;
    float acc[8];
    #pragma unroll
    for (int j = 0; j < 8; ++j) acc[j] = 0.0f;
    #pragma unroll
    for (int s = 0; s < 4; ++s){
        float wgt = ws[s] * inv;
        uint4 u = *(const uint4*)(opart + ((size_t)(s*(B_*S_) + row))*D_ + dc);
        acc[0] += wgt * bf2f(u.x & 0xffffu);  acc[1] += wgt * bf2f(u.x >> 16);
        acc[2] += wgt * bf2f(u.y & 0xffffu);  acc[3] += wgt * bf2f(u.y >> 16);
        acc[4] += wgt * bf2f(u.z & 0xffffu);  acc[5] += wgt * bf2f(u.z >> 16);
        acc[6] += wgt * bf2f(u.w & 0xffffu);  acc[7] += wgt * bf2f(u.w >> 16);
    }
    float* op = out + (size_t)row*D_ + dc;
    *(float4*)op       = make_float4(acc[0], acc[1], acc[2], acc[3]);
    *(float4*)(op + 4) = make_float4(acc[4], acc[5], acc[6], acc[7]);
}

extern "C" void kernel_launch(void* const* d_in, const int* in_sizes, int n_in,
                              void* d_out, int out_size, void* d_ws, size_t ws_size,
                              hipStream_t stream){
    const float* q = (const float*)d_in[0];
    const float* k = (const float*)d_in[1];
    const float* v = (const float*)d_in[2];
    char* ws = (char*)d_ws;
    // ws: Qb 8M | Kb 8M | Vt 8M | lse 256K | Opart(bf16) 32M  = 58,982,400 B total
    uint4* qb = (uint4*)(ws);
    uint4* kb = (uint4*)(ws + 8388608);
    unsigned short* vt = (unsigned short*)(ws + 16777216);
    float* lse = (float*)(ws + 25165824);
    unsigned short* opart = (unsigned short*)(ws + 25427968);

    cvt_qk<<<dim3(2048), dim3(256), 0, stream>>>(q, k, qb, kb);
    cvt_v_t<<<dim3(1024), dim3(256), 0, stream>>>(v, vt);
    fa_main<<<dim3(512), dim3(256), 0, stream>>>((const unsigned short*)qb,
                                                 (const unsigned short*)kb, vt,
                                                 opart, lse);
    merge_k<<<dim3(2048), dim3(256), 0, stream>>>(opart, lse, (float*)d_out);
}

// Round 4
// 252.588 us; speedup vs baseline: 1.1807x; 1.1085x over previous
//
#include <hip/hip_runtime.h>

#define B_ 4
#define S_ 4096
#define D_ 256
#define BM 128
#define BN 32
#define NSPLIT 4
#define SKEYS (S_/NSPLIT)   // 1024 keys per split
#define ITERS (SKEYS/BN)    // 32

typedef short v8s __attribute__((ext_vector_type(8)));
typedef float v16f __attribute__((ext_vector_type(16)));
typedef unsigned int v4u __attribute__((ext_vector_type(4)));

__device__ __forceinline__ unsigned short f2bf(float x){
    unsigned int u = __float_as_uint(x);
    u += 0x7fffu + ((u >> 16) & 1u);          // RNE
    return (unsigned short)(u >> 16);
}
__device__ __forceinline__ unsigned int pk2(float a, float b){
    return (unsigned int)f2bf(a) | ((unsigned int)f2bf(b) << 16);
}
__device__ __forceinline__ float bf2f(unsigned int lo16){
    return __uint_as_float(lo16 << 16);
}
// async global->LDS, 16B/lane; LDS dest = wave-uniform base + lane*16
__device__ __forceinline__ void gload_lds(const unsigned short* g, unsigned short* l){
    __builtin_amdgcn_global_load_lds(
        (const __attribute__((address_space(1))) unsigned int*)g,
        (__attribute__((address_space(3))) unsigned int*)l, 16, 0, 0);
}

// ---------- fused conversion ----------
// blocks 0..2047: Q (scaled 1/16) + K -> bf16, PRE-SWIZZLED rows (chunk ^= row&7)
// blocks 2048..3071: V (b,s,d) -> Vt (b,d,s) bf16, s-bits 3:4 XORed by (d&3)
__global__ void cvt_all(const float* __restrict__ q, const float* __restrict__ k,
                        const float* __restrict__ v,
                        uint4* __restrict__ qb, uint4* __restrict__ kb,
                        unsigned short* __restrict__ vt){
    int bx = blockIdx.x;
    if (bx < 2048){
        int gid = bx * 256 + threadIdx.x;          // one 16B chunk of Q and of K
        int row = gid >> 5, c = gid & 31;
        size_t dsti = (size_t)row*32 + (c ^ (row & 7));
        const float4* qp = (const float4*)q + (size_t)gid * 2;
        float4 a0 = qp[0], a1 = qp[1];
        const float sc = 0.0625f;                  // 1/sqrt(256)
        uint4 o;
        o.x = pk2(a0.x*sc, a0.y*sc); o.y = pk2(a0.z*sc, a0.w*sc);
        o.z = pk2(a1.x*sc, a1.y*sc); o.w = pk2(a1.z*sc, a1.w*sc);
        qb[dsti] = o;
        const float4* kp = (const float4*)k + (size_t)gid * 2;
        float4 b0 = kp[0], b1 = kp[1];
        uint4 o2;
        o2.x = pk2(b0.x, b0.y); o2.y = pk2(b0.z, b0.w);
        o2.z = pk2(b1.x, b1.y); o2.w = pk2(b1.z, b1.w);
        kb[dsti] = o2;
    } else {
        int bid = bx - 2048;                       // b(2) | dblk(2) | sblk(6)
        int b    = bid >> 8;
        int dblk = (bid >> 6) & 3;
        int sblk = bid & 63;
        int t = threadIdx.x;
        int s  = sblk*64 + (t & 63);
        int d0 = (dblk*4 + (t >> 6)) * 16;
        const float* src = v + ((size_t)(b*S_ + s))*D_ + d0;
        float4 f[4];
        #pragma unroll
        for (int i = 0; i < 4; ++i) f[i] = ((const float4*)src)[i];
        unsigned short* dstb = vt + (size_t)(b*D_ + d0)*S_;
        #pragma unroll
        for (int i = 0; i < 4; ++i){
            // component c -> d = d0+4i+c, d&3 == c; store at s ^ (c<<3)
            dstb[(size_t)(4*i+0)*S_ + (s ^ (0<<3))] = f2bf(f[i].x);
            dstb[(size_t)(4*i+1)*S_ + (s ^ (1<<3))] = f2bf(f[i].y);
            dstb[(size_t)(4*i+2)*S_ + (s ^ (2<<3))] = f2bf(f[i].z);
            dstb[(size_t)(4*i+3)*S_ + (s ^ (3<<3))] = f2bf(f[i].w);
        }
    }
}

// ---------- main flash-attention kernel ----------
// 256 thr = 4 waves; wave owns 32 queries x all BN=32 keys/iter x full d=256.
// Double-buffered staging, ONE barrier per iter; loads fly a full iteration.
__global__ __launch_bounds__(256, 2) void fa_main(
    const unsigned short* __restrict__ qb, const unsigned short* __restrict__ kb,
    const unsigned short* __restrict__ vtg,
    unsigned short* __restrict__ opart, float* __restrict__ lsep)
{
    __shared__ __align__(16) unsigned short sbuf[2][16384];   // 2 x (16KB K + 16KB V)

    int bid = blockIdx.x;
    int grp = bid & 15;                 // (b,split): KV group -> XCD slot
    int qt  = bid >> 4;
    int b = grp >> 2, split = grp & 3;
    int q0 = qt * BM;
    int tid = threadIdx.x;
    int w = tid >> 6, lane = tid & 63, hi = lane >> 5, ln = lane & 31;
    int m7 = ln & 7, m3 = ln & 3;

    const unsigned short* qg = qb  + ((size_t)(b*S_) + q0) * D_;
    const unsigned short* kg = kb  + ((size_t)(b*S_) + split*SKEYS) * D_;
    const unsigned short* vg = vtg + (size_t)(b*D_)*S_ + split*SKEYS;

    // ---- stage Q (pre-swizzled image) in 2 rounds of 64 rows; pull B-frags ----
    v8s qf[16];
    #pragma unroll
    for (int r = 0; r < 2; ++r){
        __syncthreads();
        #pragma unroll
        for (int p = 0; p < 8; ++p){
            int row  = 16*w + 2*p;
            gload_lds(qg + (size_t)(64*r + row + (lane>>5))*D_ + (lane & 31)*8,
                      &sbuf[0][row*256]);
        }
        __syncthreads();
        if ((w >> 1) == r){
            int rl = 32*(w & 1) + ln;
            #pragma unroll
            for (int f = 0; f < 16; ++f)
                qf[f] = *(const v8s*)&sbuf[0][rl*256 + (((2*f + hi) ^ m7) * 8)];
        }
    }
    __syncthreads();   // Q reads done before buffer reuse

    v16f oacc[8];
    #pragma unroll
    for (int t = 0; t < 8; ++t)
        #pragma unroll
        for (int r = 0; r < 16; ++r) oacc[t][r] = 0.0f;
    float m_run = -1e30f, l_run = 0.0f;

    // prologue: stage tile 0 into buf 0
    {
        const unsigned short* kk = kg;
        #pragma unroll
        for (int p = 0; p < 4; ++p){
            int row = 8*w + 2*p;
            gload_lds(kk + (size_t)(row + (lane>>5))*D_ + (lane & 31)*8, &sbuf[0][row*256]);
        }
        const unsigned short* vv = vg;
        #pragma unroll
        for (int p = 0; p < 4; ++p){
            int d0 = 64*w + 16*p;
            gload_lds(vv + (size_t)(d0 + (lane>>2))*S_ + (lane & 3)*8, &sbuf[0][8192 + d0*32]);
        }
    }

    for (int it = 0; it < ITERS; ++it){
        __syncthreads();               // drains vmcnt -> buf[it&1] fully staged
        int cur = it & 1;
        if (it + 1 < ITERS){           // prefetch next tile into other buffer
            const unsigned short* kk = kg + (size_t)((it+1)*BN)*D_;
            #pragma unroll
            for (int p = 0; p < 4; ++p){
                int row = 8*w + 2*p;
                gload_lds(kk + (size_t)(row + (lane>>5))*D_ + (lane & 31)*8,
                          &sbuf[cur^1][row*256]);
            }
            const unsigned short* vv = vg + (it+1)*BN;
            #pragma unroll
            for (int p = 0; p < 4; ++p){
                int d0 = 64*w + 16*p;
                gload_lds(vv + (size_t)(d0 + (lane>>2))*S_ + (lane & 3)*8,
                          &sbuf[cur^1][8192 + d0*32]);
            }
        }
        const unsigned short* Kb = &sbuf[cur][0];
        const unsigned short* Vb = &sbuf[cur][8192];

        // ---- S^T = K·Q^T (32 keys x 32 queries), two interleaved acc chains ----
        v16f sa, sb;
        #pragma unroll
        for (int r = 0; r < 16; ++r){ sa[r] = 0.0f; sb[r] = 0.0f; }
        #pragma unroll
        for (int f = 0; f < 8; ++f){
            v8s a0 = *(const v8s*)&Kb[ln*256 + (((2*f      + hi) ^ m7) * 8)];
            v8s a1 = *(const v8s*)&Kb[ln*256 + (((2*(f+8) + hi) ^ m7) * 8)];
            sa = __builtin_amdgcn_mfma_f32_32x32x16_bf16(a0, qf[f],   sa, 0, 0, 0);
            sb = __builtin_amdgcn_mfma_f32_32x32x16_bf16(a1, qf[f+8], sb, 0, 0, 0);
        }
        v16f sc;
        #pragma unroll
        for (int r = 0; r < 16; ++r) sc[r] = sa[r] + sb[r];

        // ---- wave-local online softmax ----
        float mx = sc[0];
        #pragma unroll
        for (int r = 1; r < 16; ++r) mx = fmaxf(mx, sc[r]);
        mx = fmaxf(mx, __shfl_xor(mx, 32));
        float m_new = fmaxf(m_run, mx);
        float alpha = __expf(m_run - m_new);
        m_run = m_new;

        float ls = 0.0f;
        uint2 pA[4];
        #pragma unroll
        for (int c = 0; c < 4; ++c){
            float e0 = __expf(sc[4*c+0] - m_new), e1 = __expf(sc[4*c+1] - m_new);
            float e2 = __expf(sc[4*c+2] - m_new), e3 = __expf(sc[4*c+3] - m_new);
            ls += (e0 + e1) + (e2 + e3);
            pA[c].x = pk2(e0, e1); pA[c].y = pk2(e2, e3);
        }
        ls += __shfl_xor(ls, 32);
        l_run = l_run * alpha + ls;

        // ---- P: C-layout -> B-operand via lane^32 quad exchange ----
        v8s pf[2];
        #pragma unroll
        for (int ks = 0; ks < 2; ++ks){
            uint2 snd = pA[2*ks + 1 - hi];
            uint2 rcv;
            rcv.x = (unsigned int)__shfl_xor((int)snd.x, 32);
            rcv.y = (unsigned int)__shfl_xor((int)snd.y, 32);
            uint2 lo = hi ? rcv : pA[2*ks];
            uint2 hb = hi ? pA[2*ks+1] : rcv;
            union { unsigned int u[4]; v8s v; } cc;
            cc.u[0] = lo.x; cc.u[1] = lo.y; cc.u[2] = hb.x; cc.u[3] = hb.y;
            pf[ks] = cc.v;
        }

        // rescale O only when some lane's max moved (wave-uniform branch)
        if (__any(alpha != 1.0f)){
            #pragma unroll
            for (int t = 0; t < 8; ++t)
                #pragma unroll
                for (int r = 0; r < 16; ++r) oacc[t][r] *= alpha;
        }

        // ---- O^T += V^T · P ----
        #pragma unroll
        for (int ks = 0; ks < 2; ++ks){
            #pragma unroll
            for (int t = 0; t < 8; ++t){
                v8s av = *(const v8s*)&Vb[(t*32 + ln)*32 + (((2*ks + hi) ^ m3) * 8)];
                oacc[t] = __builtin_amdgcn_mfma_f32_32x32x16_bf16(av, pf[ks], oacc[t], 0, 0, 0);
            }
        }
    }

    // ---- epilogue: normalize, per-wave LDS transpose, coalesced nt stores ----
    float inv = 1.0f / l_run;
    size_t orow0 = (size_t)(split*B_ + b)*S_ + q0 + w*32;
    if (hi == 0) lsep[orow0 + ln] = m_run + __logf(l_run);

    unsigned short* flat = &sbuf[0][0];
    unsigned short* myreg = flat + (w & 1) * 8320;       // 32 rows x 260 shorts
    #pragma unroll
    for (int rnd = 0; rnd < 2; ++rnd){
        __syncthreads();
        if ((w >> 1) == rnd){
            #pragma unroll
            for (int t = 0; t < 8; ++t)
                #pragma unroll
                for (int g = 0; g < 4; ++g){
                    uint2 u;
                    u.x = pk2(oacc[t][4*g+0]*inv, oacc[t][4*g+1]*inv);
                    u.y = pk2(oacc[t][4*g+2]*inv, oacc[t][4*g+3]*inv);
                    *(uint2*)&myreg[ln*260 + t*32 + 8*g + 4*hi] = u;
                }
            #pragma unroll
            for (int p = 0; p < 16; ++p){
                int qq = 2*p + (lane >> 5);
                int ch = lane & 31;
                v4u val = *(const v4u*)&myreg[qq*260 + ch*8];
                __builtin_nontemporal_store(val,
                    (v4u*)(opart + (orow0 + qq)*D_ + ch*8));
            }
        }
    }
}

// ---------- merge the 4 K-splits (LSE-weighted) ----------
__global__ void merge_k(const unsigned short* __restrict__ opart,
                        const float* __restrict__ lsep, float* __restrict__ out){
    int gid = blockIdx.x * 256 + threadIdx.x;   // 2048 blocks
    int row = gid >> 5;                         // b*S + q
    int dc  = (gid & 31) * 8;
    float L[4];
    #pragma unroll
    for (int s = 0; s < 4; ++s) L[s] = lsep[s*(B_*S_) + row];
    float mm = fmaxf(fmaxf(L[0], L[1]), fmaxf(L[2], L[3]));
    float wsum[4], tot = 0.0f;
    #pragma unroll
    for (int s = 0; s < 4; ++s){ wsum[s] = __expf(L[s] - mm); tot += wsum[s]; }
    float inv = 1.0f / tot;
    float acc[8];
    #pragma unroll
    for (int j = 0; j < 8; ++j) acc[j] = 0.0f;
    #pragma unroll
    for (int s = 0; s < 4; ++s){
        float wgt = wsum[s] * inv;
        uint4 u = *(const uint4*)(opart + ((size_t)(s*(B_*S_) + row))*D_ + dc);
        acc[0] += wgt * bf2f(u.x & 0xffffu);  acc[1] += wgt * bf2f(u.x >> 16);
        acc[2] += wgt * bf2f(u.y & 0xffffu);  acc[3] += wgt * bf2f(u.y >> 16);
        acc[4] += wgt * bf2f(u.z & 0xffffu);  acc[5] += wgt * bf2f(u.z >> 16);
        acc[6] += wgt * bf2f(u.w & 0xffffu);  acc[7] += wgt * bf2f(u.w >> 16);
    }
    float* op = out + (size_t)row*D_ + dc;
    *(float4*)op       = make_float4(acc[0], acc[1], acc[2], acc[3]);
    *(float4*)(op + 4) = make_float4(acc[4], acc[5], acc[6], acc[7]);
}

extern "C" void kernel_launch(void* const* d_in, const int* in_sizes, int n_in,
                              void* d_out, int out_size, void* d_ws, size_t ws_size,
                              hipStream_t stream){
    const float* q = (const float*)d_in[0];
    const float* k = (const float*)d_in[1];
    const float* v = (const float*)d_in[2];
    char* ws = (char*)d_ws;
    // ws: Qb 8M | Kb 8M | Vt 8M | lse 256K | Opart(bf16) 32M = 58,982,400 B
    uint4* qb = (uint4*)(ws);
    uint4* kb = (uint4*)(ws + 8388608);
    unsigned short* vt = (unsigned short*)(ws + 16777216);
    float* lse = (float*)(ws + 25165824);
    unsigned short* opart = (unsigned short*)(ws + 25427968);

    cvt_all<<<dim3(3072), dim3(256), 0, stream>>>(q, k, v, qb, kb, vt);
    fa_main<<<dim3(512), dim3(256), 0, stream>>>((const unsigned short*)qb,
                                                 (const unsigned short*)kb, vt,
                                                 opart, lse);
    merge_k<<<dim3(2048), dim3(256), 0, stream>>>(opart, lse, (float*)d_out);
}